// Round 5
// baseline (278.088 us; speedup 1.0000x reference)
//
#include <hip/hip_runtime.h>

typedef short short8 __attribute__((ext_vector_type(8)));
typedef unsigned short ushort8v __attribute__((ext_vector_type(8)));
typedef float f32x4 __attribute__((ext_vector_type(4)));

static __device__ __forceinline__ unsigned short f2b(float f) {
    unsigned int u = __builtin_bit_cast(unsigned int, f);
    unsigned int r = (u + 0x7fffu + ((u >> 16) & 1u)) >> 16;
    return (unsigned short)r;
}
static __device__ __forceinline__ unsigned short f2b_trunc(float f) {
    return (unsigned short)(__builtin_bit_cast(unsigned int, f) >> 16);
}
static __device__ __forceinline__ float b2f(unsigned short u) {
    return __builtin_bit_cast(float, (unsigned int)u << 16);
}
static __device__ __forceinline__ float exp2v(float x) {
    float r;
    asm("v_exp_f32 %0, %1" : "=v"(r) : "v"(x));
    return r;
}

__device__ __forceinline__ void gload16(void* lds, const void* g) {
    __builtin_amdgcn_global_load_lds(
        (const __attribute__((address_space(1))) void*)g,
        (__attribute__((address_space(3))) void*)lds, 16, 0, 0);
}

#define L2E 1.4426950408889634f

// ---------------- convert x (f32 -> bf16) ----------------
__global__ __launch_bounds__(256) void cvt_x_kernel(const float* __restrict__ x,
                                                    unsigned short* __restrict__ o, int n4) {
    int i = blockIdx.x * 256 + threadIdx.x;
    float4 f = ((const float4*)x)[i];
    ushort4 u;
    u.x = f2b(f.x); u.y = f2b(f.y); u.z = f2b(f.z); u.w = f2b(f.w);
    ((ushort4*)o)[i] = u;
}

// ---------------- transpose weight W[K][N] f32 -> Wt[N][K] bf16 ----------------
__global__ __launch_bounds__(256) void transpose_w(const float* __restrict__ W,
                                                   unsigned short* __restrict__ Wt,
                                                   int K, int N) {
    __shared__ float t[32][33];
    int kb = blockIdx.y << 5, nb = blockIdx.x << 5;
    int tx = threadIdx.x & 31, ty = threadIdx.x >> 5;  // 32 x 8
#pragma unroll
    for (int i = 0; i < 32; i += 8)
        t[ty + i][tx] = W[(size_t)(kb + ty + i) * N + nb + tx];
    __syncthreads();
#pragma unroll
    for (int i = 0; i < 32; i += 8)
        Wt[(size_t)(nb + ty + i) * K + kb + tx] = f2b(t[tx][ty + i]);
}

// ---------------- aug columns for Q/K (type+mask bias folded into MFMA) ----------------
__global__ __launch_bounds__(256) void aug_qk(const int* __restrict__ types,
                                              const int* __restrict__ nmask,
                                              const float* __restrict__ tt,
                                              unsigned short* __restrict__ Qb,
                                              unsigned short* __restrict__ Kb) {
    int t = blockIdx.x * 256 + threadIdx.x;  // 65536 threads
    int bh = t >> 10, n = t & 1023;
    int b = bh >> 3, h = bh & 7;
    int tj = types[b * 1024 + n];
    int mk = nmask[b * 1024 + n];
    float t00 = tt[h * 4], t01 = tt[h * 4 + 1], t10 = tt[h * 4 + 2], t11 = tt[h * 4 + 3];
    float bA = L2E * (t00 + (t01 - t00) * tj) + (mk ? 0.f : -1e30f);
    float bB = L2E * ((t10 - t00) + (t11 - t01 - t10 + t00) * tj);
    size_t off = ((size_t)bh * 1024 + n) * 128 + 96;
    ushort8v z = {0, 0, 0, 0, 0, 0, 0, 0};
    ushort8v qv = z, kv = z;
    qv[0] = 0x3F80u;
    qv[1] = tj ? 0x3F80u : 0u;
    kv[0] = f2b(bA);
    kv[1] = f2b(bB);
    *(ushort8v*)&Qb[off] = qv;
    *(ushort8v*)&Qb[off + 8] = z;
    *(ushort8v*)&Qb[off + 16] = z;
    *(ushort8v*)&Qb[off + 24] = z;
    *(ushort8v*)&Kb[off] = kv;
    *(ushort8v*)&Kb[off + 8] = z;
    *(ushort8v*)&Kb[off + 16] = z;
    *(ushort8v*)&Kb[off + 24] = z;
}

// ---------------- 256x256 8-wave phased GEMM: C = A[M][K] * Bt[N][K]^T + bias ----
// EPI: 0 = f32 out, 2 = gelu->bf16 out, 3 = qkv scatter (Q scaled by 1/sqrt(96)*log2e)
// LDS [2 buf][2 mat][2 kh][256 row][32 col] bf16, XOR swizzle slot^=(row>>1)&3.
// Stage unit (mat,kh) = 1024 granules of 16B; thread tid writes granules {tid, 512+tid}
// at short-offsets {wave*512 + lane*8, 4096 + wave*512 + lane*8}  (gload_lds: base+lane*16B).
// vmcnt(6) counted waits at kh tops; never 0 in-loop.
template <int EPI>
__global__ __launch_bounds__(512, 2) void gemm8p(
    const unsigned short* __restrict__ A, const unsigned short* __restrict__ Bt,
    const float* __restrict__ bias, float* __restrict__ outf,
    unsigned short* __restrict__ outb, unsigned short* __restrict__ q_o,
    unsigned short* __restrict__ k_o, unsigned short* __restrict__ v_o,
    int N, int K, int ntn, int NT) {
    __shared__ unsigned short lds[65536];  // 128 KiB
    const int tid = threadIdx.x;
    const int wave = tid >> 6, lane = tid & 63;
    const int lr = lane & 15, lg = lane >> 4;
    const int wm = wave >> 2, wn = wave & 3;
    // XCD-aware bijective swizzle (all grids % 8 == 0)
    const int nwg = gridDim.x;
    const int orig = blockIdx.x;
    const int swz = (orig & 7) * (nwg >> 3) + (orig >> 3);
    const int tm = swz / ntn, tn = swz % ntn;

    // per-thread pre-swizzled staging sources: granule g=(set*512+tid) -> row=g>>2, sl=g&3
    const unsigned short* src[2][2];
#pragma unroll
    for (int s = 0; s < 2; ++s) {
        int g = s * 512 + tid;
        int row = g >> 2, sl = g & 3;
        int colg = sl ^ ((row >> 1) & 3);
        src[0][s] = A + (size_t)(tm * 256 + row) * K + colg * 8;
        src[1][s] = Bt + (size_t)(tn * 256 + row) * K + colg * 8;
    }
    auto stage = [&](int buf, int t, int mat, int kh) {
        int coff = t * 64 + kh * 32;
        unsigned short* dst = lds + buf * 32768 + mat * 16384 + kh * 8192 + wave * 512;
        gload16(dst, src[mat][0] + coff);
        gload16(dst + 4096, src[mat][1] + coff);
    };

    f32x4 acc[8][4] = {};

    // prologue: stage tile 0 into buf 0
    stage(0, 0, 0, 0);
    stage(0, 0, 1, 0);
    stage(0, 0, 0, 1);
    stage(0, 0, 1, 1);

    for (int t = 0; t < NT; ++t) {
        const int buf = t & 1;
        const unsigned short* Al = lds + buf * 32768;
        const unsigned short* Bl = Al + 16384;
        const int t1 = (t + 1 < NT) ? t + 1 : t;
#pragma unroll
        for (int kh = 0; kh < 2; ++kh) {
            // ---- phase A: m-frags 0-3 ----
            stage(buf ^ 1, t1, 0, kh);  // A of kh for t+1
            asm volatile("s_waitcnt vmcnt(6)" ::: "memory");
            __builtin_amdgcn_s_barrier();
            short8 bfr[4], af[4];
#pragma unroll
            for (int n = 0; n < 4; ++n) {
                int row = wn * 64 + n * 16 + lr;
                bfr[n] = *(const short8*)&Bl[kh * 8192 + row * 32 + (lg ^ ((row >> 1) & 3)) * 8];
            }
#pragma unroll
            for (int m = 0; m < 4; ++m) {
                int row = wm * 128 + m * 16 + lr;
                af[m] = *(const short8*)&Al[kh * 8192 + row * 32 + (lg ^ ((row >> 1) & 3)) * 8];
            }
            __builtin_amdgcn_s_setprio(1);
#pragma unroll
            for (int m = 0; m < 4; ++m)
#pragma unroll
                for (int n = 0; n < 4; ++n)
                    acc[m][n] = __builtin_amdgcn_mfma_f32_16x16x32_bf16(af[m], bfr[n], acc[m][n], 0, 0, 0);
            __builtin_amdgcn_s_setprio(0);
            // ---- phase B: m-frags 4-7 ----
            stage(buf ^ 1, t1, 1, kh);  // B of kh for t+1
#pragma unroll
            for (int m = 0; m < 4; ++m) {
                int row = wm * 128 + 64 + m * 16 + lr;
                af[m] = *(const short8*)&Al[kh * 8192 + row * 32 + (lg ^ ((row >> 1) & 3)) * 8];
            }
            __builtin_amdgcn_s_setprio(1);
#pragma unroll
            for (int m = 0; m < 4; ++m)
#pragma unroll
                for (int n = 0; n < 4; ++n)
                    acc[4 + m][n] = __builtin_amdgcn_mfma_f32_16x16x32_bf16(af[m], bfr[n], acc[4 + m][n], 0, 0, 0);
            __builtin_amdgcn_s_setprio(0);
            __builtin_amdgcn_s_barrier();  // WAR: all kh reads done before next overwrite
        }
    }
    asm volatile("s_waitcnt vmcnt(0)" ::: "memory");  // drain trailing stages before exit

#pragma unroll
    for (int m = 0; m < 8; ++m) {
        int grb = tm * 256 + wm * 128 + m * 16 + lg * 4;
#pragma unroll
        for (int n = 0; n < 4; ++n) {
            int gc = tn * 256 + wn * 64 + n * 16 + lr;
            float bv = bias[gc];
#pragma unroll
            for (int r = 0; r < 4; ++r) {
                int gr = grb + r;
                float v = acc[m][n][r] + bv;
                if constexpr (EPI == 0) {
                    outf[(size_t)gr * N + gc] = v;
                } else if constexpr (EPI == 2) {
                    float gl = 0.5f * v * (1.f + erff(v * 0.70710678f));
                    outb[(size_t)gr * N + gc] = f2b(gl);
                } else {
                    int part = gc / 768;
                    int cc = gc - part * 768;
                    int h = cc / 96, dh = cc - h * 96;
                    int b = gr >> 10, n2 = gr & 1023;
                    size_t bh = (size_t)(b * 8 + h);
                    if (part == 0) q_o[(bh * 1024 + n2) * 128 + dh] = f2b(v * 0.14724445f);
                    else if (part == 1) k_o[(bh * 1024 + n2) * 128 + dh] = f2b(v);
                    else v_o[(bh * 96 + dh) * 1024 + n2] = f2b(v);  // V transposed
                }
            }
        }
    }
}

// ---------------- flash attention (8 waves, dbuf, aug-K, exp2 domain) ----------------
__global__ __launch_bounds__(512, 4) void attn_kernel(
    const unsigned short* __restrict__ Qb, const unsigned short* __restrict__ Kb,
    const unsigned short* __restrict__ Vt, const float* __restrict__ centers,
    const float* __restrict__ rel_emb, unsigned short* __restrict__ Y) {
    __shared__ unsigned short kv_lds[2 * 14336];  // 56 KB
    __shared__ unsigned short p_lds[8 * 1024];    // 16 KB
    __shared__ float c_lds[1024];
    __shared__ float rel_lds[41];

    const int tid = threadIdx.x;
    const int wave = tid >> 6, lane = tid & 63;
    const int lr = lane & 15, lg = lane >> 4;
    const int bh = blockIdx.x, qb = blockIdx.y;
    const int b = bh >> 3, h = bh & 7;
    const int q0 = qb * 128 + wave * 16;
    const size_t kvbase = (size_t)bh * 1024 * 128;

    c_lds[tid] = centers[b * 1024 + tid];
    c_lds[tid + 512] = centers[b * 1024 + 512 + tid];
    if (tid < 41) rel_lds[tid] = rel_emb[tid * 8 + h] * L2E;

    const unsigned short* sbase[4];
    int sstep[4];
#pragma unroll
    for (int it = 0; it < 4; ++it) {
        int g = (it < 3) ? it * 512 + tid : 1536 + wave * 64 + lane;
        if (g < 1024) {  // K granule
            int ks = g >> 8, rem = g & 255, pr = rem >> 3, sl = rem & 7;
            int so = sl ^ (pr & 7);
            int r = ((so >> 2) << 5) + pr, oct = so & 3;
            sbase[it] = Kb + kvbase + (size_t)r * 128 + ks * 32 + oct * 8;
            sstep[it] = 64 * 128;
        } else {  // V granule
            int v = g - 1024, pr = v >> 3, sl = v & 7;
            int so = sl ^ (pr & 7);
            sbase[it] = Vt + (size_t)(bh * 96 + (pr < 96 ? pr : 95)) * 1024 + so * 8;
            sstep[it] = 64;
        }
    }
    auto stage = [&](int bufb, int kt) {
        unsigned short* dst = kv_lds + bufb * 14336;
#pragma unroll
        for (int it = 0; it < 3; ++it)
            gload16(dst + it * 4096 + wave * 512, sbase[it] + (size_t)kt * sstep[it]);
        if (tid < 256)
            gload16(dst + 3 * 4096 + wave * 512, sbase[3] + (size_t)kt * sstep[3]);
    };

    short8 qa[4];
#pragma unroll
    for (int ks = 0; ks < 4; ++ks)
        qa[ks] = *(const short8*)&Qb[kvbase + (size_t)(q0 + lr) * 128 + ks * 32 + lg * 8];
    float ci20[4];
#pragma unroll
    for (int r = 0; r < 4; ++r) ci20[r] = centers[b * 1024 + q0 + lg * 4 + r] + 20.f;

    short8 vone = {};
    if (lr == 0) {
#pragma unroll
        for (int e = 0; e < 8; ++e) vone[e] = (short)0x3F80;
    }

    float m_r[4] = {-3e30f, -3e30f, -3e30f, -3e30f};
    f32x4 oacc[7] = {};

    stage(0, 0);
    asm volatile("s_waitcnt lgkmcnt(0)" ::: "memory");

    for (int kt = 0; kt < 16; ++kt) {
        const int buf = kt & 1;
        if (kt < 15) {
            stage(buf ^ 1, kt + 1);
            asm volatile("s_waitcnt vmcnt(3)" ::: "memory");
        } else {
            asm volatile("s_waitcnt vmcnt(0)" ::: "memory");
        }
        __builtin_amdgcn_s_barrier();
        const unsigned short* kv = kv_lds + buf * 14336;

        f32x4 s[4] = {};
#pragma unroll
        for (int jf = 0; jf < 4; ++jf) {
            int pr = ((jf & 1) << 4) + lr;
            int slp = (((jf >> 1) << 2) + lg) ^ (lr & 7);
#pragma unroll
            for (int ks = 0; ks < 4; ++ks) {
                short8 kf = *(const short8*)&kv[ks * 2048 + pr * 64 + slp * 8];
                s[jf] = __builtin_amdgcn_mfma_f32_16x16x32_bf16(qa[ks], kf, s[jf], 0, 0, 0);
            }
        }

#pragma unroll
        for (int jf = 0; jf < 4; ++jf) {
            float cj = c_lds[kt * 64 + jf * 16 + lr];
#pragma unroll
            for (int r = 0; r < 4; ++r) {
                float idxf = __builtin_amdgcn_fmed3f(ci20[r] - cj, 0.f, 40.f);
                s[jf][r] += rel_lds[(int)rintf(idxf)];
            }
        }

#pragma unroll
        for (int r = 0; r < 4; ++r) {
            float mx = fmaxf(fmaxf(s[0][r], s[1][r]), fmaxf(s[2][r], s[3][r]));
#pragma unroll
            for (int off = 1; off < 16; off <<= 1) mx = fmaxf(mx, __shfl_xor(mx, off));
            if (!__all(mx <= m_r[r] + 8.f)) {
                float mn = fmaxf(m_r[r], mx);
                float al = exp2v(m_r[r] - mn);
                m_r[r] = mn;
#pragma unroll
                for (int nf = 0; nf < 7; ++nf) oacc[nf][r] *= al;
            }
#pragma unroll
            for (int jf = 0; jf < 4; ++jf) s[jf][r] = exp2v(s[jf][r] - m_r[r]);
        }

#pragma unroll
        for (int jf = 0; jf < 4; ++jf)
#pragma unroll
            for (int r = 0; r < 4; ++r) {
                int row = lg * 4 + r, col = jf * 16 + lr;
                int gp = (col >> 3) ^ (row & 7);
                p_lds[wave * 1024 + row * 64 + gp * 8 + (col & 7)] = f2b_trunc(s[jf][r]);
            }
        asm volatile("s_waitcnt lgkmcnt(0)" ::: "memory");
        short8 pa[2];
#pragma unroll
        for (int js = 0; js < 2; ++js) {
            int slp = ((js << 2) + lg) ^ (lr & 7);
            pa[js] = *(const short8*)&p_lds[wave * 1024 + lr * 64 + slp * 8];
        }

#pragma unroll
        for (int nf = 0; nf < 6; ++nf) {
            int vrow = nf * 16 + lr;
#pragma unroll
            for (int js = 0; js < 2; ++js) {
                int slp = ((js << 2) + lg) ^ (lr & 7);
                short8 vf = *(const short8*)&kv[8192 + vrow * 64 + slp * 8];
                oacc[nf] = __builtin_amdgcn_mfma_f32_16x16x32_bf16(pa[js], vf, oacc[nf], 0, 0, 0);
            }
        }
#pragma unroll
        for (int js = 0; js < 2; ++js)
            oacc[6] = __builtin_amdgcn_mfma_f32_16x16x32_bf16(pa[js], vone, oacc[6], 0, 0, 0);
        __builtin_amdgcn_s_barrier();
    }

#pragma unroll
    for (int r = 0; r < 4; ++r) {
        float l = __shfl(oacc[6][r], lane & 48);
        float inv = (l > 0.f) ? 1.f / l : 0.f;
        int qi = q0 + lg * 4 + r;
#pragma unroll
        for (int nf = 0; nf < 6; ++nf)
            Y[((size_t)b * 1024 + qi) * 768 + h * 96 + nf * 16 + lr] = f2b(oacc[nf][r] * inv);
    }
}

// ---------------- layernorm with residual add ----------------
template <bool IN1BF>
__global__ __launch_bounds__(256) void ln_kernel(const void* __restrict__ in1,
                                                 const float* __restrict__ in2,
                                                 const float* __restrict__ g,
                                                 const float* __restrict__ be,
                                                 float* __restrict__ of,
                                                 unsigned short* __restrict__ ob) {
    int row = blockIdx.x;
    int tid = threadIdx.x;
    size_t base = (size_t)row * 768;
    float v[3]; int c[3];
#pragma unroll
    for (int i = 0; i < 3; ++i) {
        c[i] = tid + i * 256;
        float a = IN1BF ? b2f(((const unsigned short*)in1)[base + c[i]])
                        : ((const float*)in1)[base + c[i]];
        v[i] = a + in2[base + c[i]];
    }
    float s1 = v[0] + v[1] + v[2];
    float s2 = v[0] * v[0] + v[1] * v[1] + v[2] * v[2];
#pragma unroll
    for (int off = 32; off > 0; off >>= 1) {
        s1 += __shfl_xor(s1, off);
        s2 += __shfl_xor(s2, off);
    }
    __shared__ float red[8];
    if ((tid & 63) == 0) { red[tid >> 6] = s1; red[4 + (tid >> 6)] = s2; }
    __syncthreads();
    s1 = red[0] + red[1] + red[2] + red[3];
    s2 = red[4] + red[5] + red[6] + red[7];
    float mu = s1 * (1.f / 768.f);
    float var = s2 * (1.f / 768.f) - mu * mu;
    float inv = rsqrtf(var + 1e-5f);
#pragma unroll
    for (int i = 0; i < 3; ++i) {
        float o = (v[i] - mu) * inv * g[c[i]] + be[c[i]];
        if (of) of[base + c[i]] = o;
        if (ob) ob[base + c[i]] = f2b(o);
    }
}

extern "C" void kernel_launch(void* const* d_in, const int* in_sizes, int n_in,
                              void* d_out, int out_size, void* d_ws, size_t ws_size,
                              hipStream_t stream) {
    const float* x     = (const float*)d_in[0];
    const int*   nmask = (const int*)d_in[1];
    const float* cent  = (const float*)d_in[2];
    const int*   types = (const int*)d_in[3];
    const float* qkv_w = (const float*)d_in[4];
    const float* qkv_b = (const float*)d_in[5];
    const float* out_w = (const float*)d_in[6];
    const float* out_b = (const float*)d_in[7];
    const float* ff1_w = (const float*)d_in[8];
    const float* ff1_b = (const float*)d_in[9];
    const float* ff2_w = (const float*)d_in[10];
    const float* ff2_b = (const float*)d_in[11];
    const float* ln1_g = (const float*)d_in[12];
    const float* ln1_b = (const float*)d_in[13];
    const float* ln2_g = (const float*)d_in[14];
    const float* ln2_b = (const float*)d_in[15];
    const float* rel   = (const float*)d_in[16];
    const float* ttp   = (const float*)d_in[17];

    char* w = (char*)d_ws;
    auto alloc = [&](size_t bytes) {
        char* p = w;
        w += (bytes + 255) & ~(size_t)255;
        return p;
    };
    unsigned short* xb  = (unsigned short*)alloc(8192ull * 768 * 2);   // x bf16; reused as Y
    unsigned short* qwT = (unsigned short*)alloc(2304ull * 768 * 2);
    unsigned short* owT = (unsigned short*)alloc(768ull * 768 * 2);
    unsigned short* f1T = (unsigned short*)alloc(1024ull * 768 * 2);
    unsigned short* f2T = (unsigned short*)alloc(768ull * 1024 * 2);
    unsigned short* Qb  = (unsigned short*)alloc(64ull * 1024 * 128 * 2);
    unsigned short* Kb  = (unsigned short*)alloc(64ull * 1024 * 128 * 2);
    unsigned short* Vt  = (unsigned short*)alloc(64ull * 96 * 1024 * 2);
    float*          ao  = (float*)alloc(8192ull * 768 * 4);
    unsigned short* h1b = (unsigned short*)alloc(8192ull * 768 * 2);
    unsigned short* ffa = Qb;  // alias: Qb dead after attn

    cvt_x_kernel<<<6144, 256, 0, stream>>>(x, xb, 8192 * 768 / 4);
    transpose_w<<<dim3(2304 / 32, 768 / 32), 256, 0, stream>>>(qkv_w, qwT, 768, 2304);
    transpose_w<<<dim3(768 / 32, 768 / 32), 256, 0, stream>>>(out_w, owT, 768, 768);
    transpose_w<<<dim3(1024 / 32, 768 / 32), 256, 0, stream>>>(ff1_w, f1T, 768, 1024);
    transpose_w<<<dim3(768 / 32, 1024 / 32), 256, 0, stream>>>(ff2_w, f2T, 1024, 768);

    // QKV: M=8192 N=2304 K=768 -> 32x9 = 288 blocks
    gemm8p<3><<<288, 512, 0, stream>>>(xb, qwT, qkv_b, nullptr, nullptr,
                                       Qb, Kb, Vt, 2304, 768, 9, 12);
    aug_qk<<<256, 256, 0, stream>>>(types, nmask, ttp, Qb, Kb);
    attn_kernel<<<dim3(64, 8), 512, 0, stream>>>(Qb, Kb, Vt, cent, rel, xb);
    // out proj: N=768 K=768 -> 32x3 = 96 blocks
    gemm8p<0><<<96, 512, 0, stream>>>(xb, owT, out_b, ao, nullptr,
                                      nullptr, nullptr, nullptr, 768, 768, 3, 12);
    ln_kernel<false><<<8192, 256, 0, stream>>>(x, ao, ln1_g, ln1_b, nullptr, h1b);
    // ff1+gelu: N=1024 K=768 -> 32x4 = 128 blocks
    gemm8p<2><<<128, 512, 0, stream>>>(h1b, f1T, ff1_b, nullptr, ffa,
                                       nullptr, nullptr, nullptr, 1024, 768, 4, 12);
    // ff2: N=768 K=1024 -> 96 blocks
    gemm8p<0><<<96, 512, 0, stream>>>(ffa, f2T, ff2_b, ao, nullptr,
                                      nullptr, nullptr, nullptr, 768, 1024, 3, 16);
    ln_kernel<true><<<8192, 256, 0, stream>>>(h1b, ao, ln2_g, ln2_b, (float*)d_out, nullptr);
}

// Round 6
// 236.105 us; speedup vs baseline: 1.1778x; 1.1778x over previous
//
#include <hip/hip_runtime.h>

typedef short short8 __attribute__((ext_vector_type(8)));
typedef unsigned short ushort8v __attribute__((ext_vector_type(8)));
typedef float f32x4 __attribute__((ext_vector_type(4)));

static __device__ __forceinline__ unsigned short f2b(float f) {
    unsigned int u = __builtin_bit_cast(unsigned int, f);
    unsigned int r = (u + 0x7fffu + ((u >> 16) & 1u)) >> 16;
    return (unsigned short)r;
}
static __device__ __forceinline__ unsigned short f2b_trunc(float f) {
    return (unsigned short)(__builtin_bit_cast(unsigned int, f) >> 16);
}
static __device__ __forceinline__ float b2f(unsigned short u) {
    return __builtin_bit_cast(float, (unsigned int)u << 16);
}
static __device__ __forceinline__ float exp2v(float x) {
    float r;
    asm("v_exp_f32 %0, %1" : "=v"(r) : "v"(x));
    return r;
}

__device__ __forceinline__ void gload16(void* lds, const void* g) {
    __builtin_amdgcn_global_load_lds(
        (const __attribute__((address_space(1))) void*)g,
        (__attribute__((address_space(3))) void*)lds, 16, 0, 0);
}

#define L2E 1.4426950408889634f

// ---------------- convert x (f32 -> bf16) ----------------
__global__ __launch_bounds__(256) void cvt_x_kernel(const float* __restrict__ x,
                                                    unsigned short* __restrict__ o, int n4) {
    int i = blockIdx.x * 256 + threadIdx.x;
    float4 f = ((const float4*)x)[i];
    ushort4 u;
    u.x = f2b(f.x); u.y = f2b(f.y); u.z = f2b(f.z); u.w = f2b(f.w);
    ((ushort4*)o)[i] = u;
}

// ---------------- transpose weight W[K][N] f32 -> Wt[N][K] bf16 ----------------
__global__ __launch_bounds__(256) void transpose_w(const float* __restrict__ W,
                                                   unsigned short* __restrict__ Wt,
                                                   int K, int N) {
    __shared__ float t[32][33];
    int kb = blockIdx.y << 5, nb = blockIdx.x << 5;
    int tx = threadIdx.x & 31, ty = threadIdx.x >> 5;  // 32 x 8
#pragma unroll
    for (int i = 0; i < 32; i += 8)
        t[ty + i][tx] = W[(size_t)(kb + ty + i) * N + nb + tx];
    __syncthreads();
#pragma unroll
    for (int i = 0; i < 32; i += 8)
        Wt[(size_t)(nb + ty + i) * K + kb + tx] = f2b(t[tx][ty + i]);
}

// ---------------- aug columns for Q/K (type+mask bias folded into MFMA) ----------------
__global__ __launch_bounds__(256) void aug_qk(const int* __restrict__ types,
                                              const int* __restrict__ nmask,
                                              const float* __restrict__ tt,
                                              unsigned short* __restrict__ Qb,
                                              unsigned short* __restrict__ Kb) {
    int t = blockIdx.x * 256 + threadIdx.x;  // 65536 threads
    int bh = t >> 10, n = t & 1023;
    int b = bh >> 3, h = bh & 7;
    int tj = types[b * 1024 + n];
    int mk = nmask[b * 1024 + n];
    float t00 = tt[h * 4], t01 = tt[h * 4 + 1], t10 = tt[h * 4 + 2], t11 = tt[h * 4 + 3];
    float bA = L2E * (t00 + (t01 - t00) * tj) + (mk ? 0.f : -1e30f);
    float bB = L2E * ((t10 - t00) + (t11 - t01 - t10 + t00) * tj);
    size_t off = ((size_t)bh * 1024 + n) * 128 + 96;
    ushort8v z = {0, 0, 0, 0, 0, 0, 0, 0};
    ushort8v qv = z, kv = z;
    qv[0] = 0x3F80u;
    qv[1] = tj ? 0x3F80u : 0u;
    kv[0] = f2b(bA);
    kv[1] = f2b(bB);
    *(ushort8v*)&Qb[off] = qv;
    *(ushort8v*)&Qb[off + 8] = z;
    *(ushort8v*)&Qb[off + 16] = z;
    *(ushort8v*)&Qb[off + 24] = z;
    *(ushort8v*)&Kb[off] = kv;
    *(ushort8v*)&Kb[off + 8] = z;
    *(ushort8v*)&Kb[off + 16] = z;
    *(ushort8v*)&Kb[off + 24] = z;
}

// ---------------- 128x128 BK=64 2-phase GEMM: C = A[M][K] * Bt[N][K]^T + bias ----
// EPI: 0 = f32 out, 2 = gelu->bf16 out, 3 = qkv scatter (Q scaled by 1/sqrt(96)*log2e)
// Double-buffered 32KiB LDS [buf][128 row][8 slot^(row&7)][8 shorts]; stage(t+1) issued
// before compute(t); one vmcnt(0)+barrier per K-step (T3-minimum, m248v2).
template <int EPI>
__global__ __launch_bounds__(256, 2) void gemm2p(
    const unsigned short* __restrict__ A, const unsigned short* __restrict__ Bt,
    const float* __restrict__ bias, float* __restrict__ outf,
    unsigned short* __restrict__ outb, unsigned short* __restrict__ q_o,
    unsigned short* __restrict__ k_o, unsigned short* __restrict__ v_o,
    int N, int K, int ntn, int NT) {
    __shared__ unsigned short a_lds[2][8192];
    __shared__ unsigned short b_lds[2][8192];
    const int tid = threadIdx.x;
    const int wave = tid >> 6, lane = tid & 63;
    const int lr = lane & 15, lg = lane >> 4;
    const int wm = wave >> 1, wn = wave & 1;
    // XCD-aware bijective swizzle (all grids % 8 == 0)
    const int nwg = gridDim.x;
    const int orig = blockIdx.x;
    const int swz = (orig & 7) * (nwg >> 3) + (orig >> 3);
    const int tm = swz / ntn, tn = swz % ntn;

    // staging sources: granule g = i*256+tid -> row=g>>3, sl=g&7, src col-granule = sl^(row&7)
    const unsigned short* srcA[4];
    const unsigned short* srcB[4];
#pragma unroll
    for (int i = 0; i < 4; ++i) {
        int g = i * 256 + tid;
        int row = g >> 3, sl = g & 7;
        int colg = sl ^ (row & 7);
        srcA[i] = A + (size_t)(tm * 128 + row) * K + colg * 8;
        srcB[i] = Bt + (size_t)(tn * 128 + row) * K + colg * 8;
    }
    auto stage = [&](int buf, int k0) {
#pragma unroll
        for (int i = 0; i < 4; ++i) {
            gload16(&a_lds[buf][i * 2048 + wave * 512], srcA[i] + k0);
            gload16(&b_lds[buf][i * 2048 + wave * 512], srcB[i] + k0);
        }
    };

    f32x4 acc[4][4] = {};

    stage(0, 0);
    asm volatile("s_waitcnt vmcnt(0)" ::: "memory");
    __builtin_amdgcn_s_barrier();

    for (int t = 0; t < NT; ++t) {
        const int buf = t & 1;
        if (t + 1 < NT) stage(buf ^ 1, (t + 1) * 64);
#pragma unroll
        for (int ks = 0; ks < 2; ++ks) {
            short8 af[4], bfr[4];
#pragma unroll
            for (int mf = 0; mf < 4; ++mf) {
                int row = wm * 64 + mf * 16 + lr;
                int slot = (ks * 4 + lg) ^ (row & 7);
                af[mf] = *(const short8*)&a_lds[buf][row * 64 + slot * 8];
            }
#pragma unroll
            for (int nf = 0; nf < 4; ++nf) {
                int row = wn * 64 + nf * 16 + lr;
                int slot = (ks * 4 + lg) ^ (row & 7);
                bfr[nf] = *(const short8*)&b_lds[buf][row * 64 + slot * 8];
            }
#pragma unroll
            for (int mf = 0; mf < 4; ++mf)
#pragma unroll
                for (int nf = 0; nf < 4; ++nf)
                    acc[mf][nf] = __builtin_amdgcn_mfma_f32_16x16x32_bf16(af[mf], bfr[nf], acc[mf][nf], 0, 0, 0);
        }
        asm volatile("s_waitcnt vmcnt(0)" ::: "memory");
        __builtin_amdgcn_s_barrier();
    }

#pragma unroll
    for (int mf = 0; mf < 4; ++mf) {
        int grb = tm * 128 + wm * 64 + mf * 16 + lg * 4;
#pragma unroll
        for (int nf = 0; nf < 4; ++nf) {
            int gc = tn * 128 + wn * 64 + nf * 16 + lr;
            float bv = bias[gc];
#pragma unroll
            for (int r = 0; r < 4; ++r) {
                int gr = grb + r;
                float v = acc[mf][nf][r] + bv;
                if constexpr (EPI == 0) {
                    outf[(size_t)gr * N + gc] = v;
                } else if constexpr (EPI == 2) {
                    float gl = 0.5f * v * (1.f + erff(v * 0.70710678f));
                    outb[(size_t)gr * N + gc] = f2b(gl);
                } else {
                    int part = gc / 768;
                    int cc = gc - part * 768;
                    int h = cc / 96, dh = cc - h * 96;
                    int b = gr >> 10, n2 = gr & 1023;
                    size_t bh = (size_t)(b * 8 + h);
                    if (part == 0) q_o[(bh * 1024 + n2) * 128 + dh] = f2b(v * 0.14724445f);
                    else if (part == 1) k_o[(bh * 1024 + n2) * 128 + dh] = f2b(v);
                    else v_o[(bh * 96 + dh) * 1024 + n2] = f2b(v);  // V transposed
                }
            }
        }
    }
}

// ---------------- flash attention (8 waves, dbuf, aug-K, exp2 domain) ----------------
__global__ __launch_bounds__(512, 4) void attn_kernel(
    const unsigned short* __restrict__ Qb, const unsigned short* __restrict__ Kb,
    const unsigned short* __restrict__ Vt, const float* __restrict__ centers,
    const float* __restrict__ rel_emb, unsigned short* __restrict__ Y) {
    __shared__ unsigned short kv_lds[2 * 14336];  // 56 KB
    __shared__ unsigned short p_lds[8 * 1024];    // 16 KB
    __shared__ float c_lds[1024];
    __shared__ float rel_lds[41];

    const int tid = threadIdx.x;
    const int wave = tid >> 6, lane = tid & 63;
    const int lr = lane & 15, lg = lane >> 4;
    const int bh = blockIdx.x, qb = blockIdx.y;
    const int b = bh >> 3, h = bh & 7;
    const int q0 = qb * 128 + wave * 16;
    const size_t kvbase = (size_t)bh * 1024 * 128;

    c_lds[tid] = centers[b * 1024 + tid];
    c_lds[tid + 512] = centers[b * 1024 + 512 + tid];
    if (tid < 41) rel_lds[tid] = rel_emb[tid * 8 + h] * L2E;

    const unsigned short* sbase[4];
    int sstep[4];
#pragma unroll
    for (int it = 0; it < 4; ++it) {
        int g = (it < 3) ? it * 512 + tid : 1536 + wave * 64 + lane;
        if (g < 1024) {  // K granule
            int ks = g >> 8, rem = g & 255, pr = rem >> 3, sl = rem & 7;
            int so = sl ^ (pr & 7);
            int r = ((so >> 2) << 5) + pr, oct = so & 3;
            sbase[it] = Kb + kvbase + (size_t)r * 128 + ks * 32 + oct * 8;
            sstep[it] = 64 * 128;
        } else {  // V granule
            int v = g - 1024, pr = v >> 3, sl = v & 7;
            int so = sl ^ (pr & 7);
            sbase[it] = Vt + (size_t)(bh * 96 + (pr < 96 ? pr : 95)) * 1024 + so * 8;
            sstep[it] = 64;
        }
    }
    auto stage = [&](int bufb, int kt) {
        unsigned short* dst = kv_lds + bufb * 14336;
#pragma unroll
        for (int it = 0; it < 3; ++it)
            gload16(dst + it * 4096 + wave * 512, sbase[it] + (size_t)kt * sstep[it]);
        if (tid < 256)
            gload16(dst + 3 * 4096 + wave * 512, sbase[3] + (size_t)kt * sstep[3]);
    };

    short8 qa[4];
#pragma unroll
    for (int ks = 0; ks < 4; ++ks)
        qa[ks] = *(const short8*)&Qb[kvbase + (size_t)(q0 + lr) * 128 + ks * 32 + lg * 8];
    float ci20[4];
#pragma unroll
    for (int r = 0; r < 4; ++r) ci20[r] = centers[b * 1024 + q0 + lg * 4 + r] + 20.f;

    short8 vone = {};
    if (lr == 0) {
#pragma unroll
        for (int e = 0; e < 8; ++e) vone[e] = (short)0x3F80;
    }

    float m_r[4] = {-3e30f, -3e30f, -3e30f, -3e30f};
    f32x4 oacc[7] = {};

    stage(0, 0);
    asm volatile("s_waitcnt lgkmcnt(0)" ::: "memory");

    for (int kt = 0; kt < 16; ++kt) {
        const int buf = kt & 1;
        if (kt < 15) {
            stage(buf ^ 1, kt + 1);
            asm volatile("s_waitcnt vmcnt(3)" ::: "memory");
        } else {
            asm volatile("s_waitcnt vmcnt(0)" ::: "memory");
        }
        __builtin_amdgcn_s_barrier();
        const unsigned short* kv = kv_lds + buf * 14336;

        f32x4 s[4] = {};
#pragma unroll
        for (int jf = 0; jf < 4; ++jf) {
            int pr = ((jf & 1) << 4) + lr;
            int slp = (((jf >> 1) << 2) + lg) ^ (lr & 7);
#pragma unroll
            for (int ks = 0; ks < 4; ++ks) {
                short8 kf = *(const short8*)&kv[ks * 2048 + pr * 64 + slp * 8];
                s[jf] = __builtin_amdgcn_mfma_f32_16x16x32_bf16(qa[ks], kf, s[jf], 0, 0, 0);
            }
        }

#pragma unroll
        for (int jf = 0; jf < 4; ++jf) {
            float cj = c_lds[kt * 64 + jf * 16 + lr];
#pragma unroll
            for (int r = 0; r < 4; ++r) {
                float idxf = __builtin_amdgcn_fmed3f(ci20[r] - cj, 0.f, 40.f);
                s[jf][r] += rel_lds[(int)rintf(idxf)];
            }
        }

#pragma unroll
        for (int r = 0; r < 4; ++r) {
            float mx = fmaxf(fmaxf(s[0][r], s[1][r]), fmaxf(s[2][r], s[3][r]));
#pragma unroll
            for (int off = 1; off < 16; off <<= 1) mx = fmaxf(mx, __shfl_xor(mx, off));
            if (!__all(mx <= m_r[r] + 8.f)) {
                float mn = fmaxf(m_r[r], mx);
                float al = exp2v(m_r[r] - mn);
                m_r[r] = mn;
#pragma unroll
                for (int nf = 0; nf < 7; ++nf) oacc[nf][r] *= al;
            }
#pragma unroll
            for (int jf = 0; jf < 4; ++jf) s[jf][r] = exp2v(s[jf][r] - m_r[r]);
        }

#pragma unroll
        for (int jf = 0; jf < 4; ++jf)
#pragma unroll
            for (int r = 0; r < 4; ++r) {
                int row = lg * 4 + r, col = jf * 16 + lr;
                int gp = (col >> 3) ^ (row & 7);
                p_lds[wave * 1024 + row * 64 + gp * 8 + (col & 7)] = f2b_trunc(s[jf][r]);
            }
        asm volatile("s_waitcnt lgkmcnt(0)" ::: "memory");
        short8 pa[2];
#pragma unroll
        for (int js = 0; js < 2; ++js) {
            int slp = ((js << 2) + lg) ^ (lr & 7);
            pa[js] = *(const short8*)&p_lds[wave * 1024 + lr * 64 + slp * 8];
        }

#pragma unroll
        for (int nf = 0; nf < 6; ++nf) {
            int vrow = nf * 16 + lr;
#pragma unroll
            for (int js = 0; js < 2; ++js) {
                int slp = ((js << 2) + lg) ^ (lr & 7);
                short8 vf = *(const short8*)&kv[8192 + vrow * 64 + slp * 8];
                oacc[nf] = __builtin_amdgcn_mfma_f32_16x16x32_bf16(pa[js], vf, oacc[nf], 0, 0, 0);
            }
        }
#pragma unroll
        for (int js = 0; js < 2; ++js)
            oacc[6] = __builtin_amdgcn_mfma_f32_16x16x32_bf16(pa[js], vone, oacc[6], 0, 0, 0);
        __builtin_amdgcn_s_barrier();
    }

#pragma unroll
    for (int r = 0; r < 4; ++r) {
        float l = __shfl(oacc[6][r], lane & 48);
        float inv = (l > 0.f) ? 1.f / l : 0.f;
        int qi = q0 + lg * 4 + r;
#pragma unroll
        for (int nf = 0; nf < 6; ++nf)
            Y[((size_t)b * 1024 + qi) * 768 + h * 96 + nf * 16 + lr] = f2b(oacc[nf][r] * inv);
    }
}

// ---------------- layernorm with residual add ----------------
template <bool IN1BF>
__global__ __launch_bounds__(256) void ln_kernel(const void* __restrict__ in1,
                                                 const float* __restrict__ in2,
                                                 const float* __restrict__ g,
                                                 const float* __restrict__ be,
                                                 float* __restrict__ of,
                                                 unsigned short* __restrict__ ob) {
    int row = blockIdx.x;
    int tid = threadIdx.x;
    size_t base = (size_t)row * 768;
    float v[3]; int c[3];
#pragma unroll
    for (int i = 0; i < 3; ++i) {
        c[i] = tid + i * 256;
        float a = IN1BF ? b2f(((const unsigned short*)in1)[base + c[i]])
                        : ((const float*)in1)[base + c[i]];
        v[i] = a + in2[base + c[i]];
    }
    float s1 = v[0] + v[1] + v[2];
    float s2 = v[0] * v[0] + v[1] * v[1] + v[2] * v[2];
#pragma unroll
    for (int off = 32; off > 0; off >>= 1) {
        s1 += __shfl_xor(s1, off);
        s2 += __shfl_xor(s2, off);
    }
    __shared__ float red[8];
    if ((tid & 63) == 0) { red[tid >> 6] = s1; red[4 + (tid >> 6)] = s2; }
    __syncthreads();
    s1 = red[0] + red[1] + red[2] + red[3];
    s2 = red[4] + red[5] + red[6] + red[7];
    float mu = s1 * (1.f / 768.f);
    float var = s2 * (1.f / 768.f) - mu * mu;
    float inv = rsqrtf(var + 1e-5f);
#pragma unroll
    for (int i = 0; i < 3; ++i) {
        float o = (v[i] - mu) * inv * g[c[i]] + be[c[i]];
        if (of) of[base + c[i]] = o;
        if (ob) ob[base + c[i]] = f2b(o);
    }
}

extern "C" void kernel_launch(void* const* d_in, const int* in_sizes, int n_in,
                              void* d_out, int out_size, void* d_ws, size_t ws_size,
                              hipStream_t stream) {
    const float* x     = (const float*)d_in[0];
    const int*   nmask = (const int*)d_in[1];
    const float* cent  = (const float*)d_in[2];
    const int*   types = (const int*)d_in[3];
    const float* qkv_w = (const float*)d_in[4];
    const float* qkv_b = (const float*)d_in[5];
    const float* out_w = (const float*)d_in[6];
    const float* out_b = (const float*)d_in[7];
    const float* ff1_w = (const float*)d_in[8];
    const float* ff1_b = (const float*)d_in[9];
    const float* ff2_w = (const float*)d_in[10];
    const float* ff2_b = (const float*)d_in[11];
    const float* ln1_g = (const float*)d_in[12];
    const float* ln1_b = (const float*)d_in[13];
    const float* ln2_g = (const float*)d_in[14];
    const float* ln2_b = (const float*)d_in[15];
    const float* rel   = (const float*)d_in[16];
    const float* ttp   = (const float*)d_in[17];

    char* w = (char*)d_ws;
    auto alloc = [&](size_t bytes) {
        char* p = w;
        w += (bytes + 255) & ~(size_t)255;
        return p;
    };
    unsigned short* xb  = (unsigned short*)alloc(8192ull * 768 * 2);   // x bf16; reused as Y
    unsigned short* qwT = (unsigned short*)alloc(2304ull * 768 * 2);
    unsigned short* owT = (unsigned short*)alloc(768ull * 768 * 2);
    unsigned short* f1T = (unsigned short*)alloc(1024ull * 768 * 2);
    unsigned short* f2T = (unsigned short*)alloc(768ull * 1024 * 2);
    unsigned short* Qb  = (unsigned short*)alloc(64ull * 1024 * 128 * 2);
    unsigned short* Kb  = (unsigned short*)alloc(64ull * 1024 * 128 * 2);
    unsigned short* Vt  = (unsigned short*)alloc(64ull * 96 * 1024 * 2);
    float*          ao  = (float*)alloc(8192ull * 768 * 4);
    unsigned short* h1b = (unsigned short*)alloc(8192ull * 768 * 2);
    unsigned short* ffa = Qb;  // alias: Qb dead after attn

    cvt_x_kernel<<<6144, 256, 0, stream>>>(x, xb, 8192 * 768 / 4);
    transpose_w<<<dim3(2304 / 32, 768 / 32), 256, 0, stream>>>(qkv_w, qwT, 768, 2304);
    transpose_w<<<dim3(768 / 32, 768 / 32), 256, 0, stream>>>(out_w, owT, 768, 768);
    transpose_w<<<dim3(1024 / 32, 768 / 32), 256, 0, stream>>>(ff1_w, f1T, 768, 1024);
    transpose_w<<<dim3(768 / 32, 1024 / 32), 256, 0, stream>>>(ff2_w, f2T, 1024, 768);

    // QKV: M=8192 N=2304 K=768 -> 64x18 = 1152 blocks
    gemm2p<3><<<1152, 256, 0, stream>>>(xb, qwT, qkv_b, nullptr, nullptr,
                                        Qb, Kb, Vt, 2304, 768, 18, 12);
    aug_qk<<<256, 256, 0, stream>>>(types, nmask, ttp, Qb, Kb);
    attn_kernel<<<dim3(64, 8), 512, 0, stream>>>(Qb, Kb, Vt, cent, rel, xb);
    // out proj: N=768 K=768 -> 64x6 = 384 blocks
    gemm2p<0><<<384, 256, 0, stream>>>(xb, owT, out_b, ao, nullptr,
                                       nullptr, nullptr, nullptr, 768, 768, 6, 12);
    ln_kernel<false><<<8192, 256, 0, stream>>>(x, ao, ln1_g, ln1_b, nullptr, h1b);
    // ff1+gelu: N=1024 K=768 -> 64x8 = 512 blocks
    gemm2p<2><<<512, 256, 0, stream>>>(h1b, f1T, ff1_b, nullptr, ffa,
                                       nullptr, nullptr, nullptr, 1024, 768, 8, 12);
    // ff2: N=768 K=1024 -> 64x6 = 384 blocks, NT=16
    gemm2p<0><<<384, 256, 0, stream>>>(ffa, f2T, ff2_b, ao, nullptr,
                                       nullptr, nullptr, nullptr, 768, 1024, 6, 16);
    ln_kernel<true><<<8192, 256, 0, stream>>>(h1b, ao, ln2_g, ln2_b, (float*)d_out, nullptr);
}